// Round 10
// baseline (65.056 us; speedup 1.0000x reference)
//
#include <hip/hip_runtime.h>

// B=4, LQ=256, LK=512, DQ=DK=DV=256, H=128
#define B_   4
#define LQ_  256
#define LK_  512
#define DQK_ 256
#define DV_  256
#define H_   128

#define TANH_C 2.8853900817779268f   // 2*log2(e): tanh(x) = 1 - 2/(exp2(TANH_C*x)+1)
#define L2E    1.4426950408889634f
#define NQBLK (B_ * LQ_ / 4)         // 256 q-proj blocks (TILE=4)
#define NKBLK (B_ * LK_ / 4)         // 512 k-proj blocks

// MEASUREMENT ROUND: attn body repeated REP_ times (idempotent) so the attn
// dispatch exceeds the harness's 39-41 us ws-poison fills and surfaces in
// rocprof's top-5 with real counters. Kernel is otherwise bit-identical to R9.
#define REP_ 4

// ---------------------------------------------------------------------------
// proj_kernel (round-4 exact, proven): fused q+k projection. TILE=4, 128 thr.
// ---------------------------------------------------------------------------
__global__ __launch_bounds__(128) void proj_kernel(const float* __restrict__ Q,
                                                   const float* __restrict__ K,
                                                   const float* __restrict__ Wq,
                                                   const float* __restrict__ Wk,
                                                   float* __restrict__ eq,
                                                   float* __restrict__ ekT) {
    const int blk = blockIdx.x;
    const bool isq = blk < NQBLK;
    const float* in = isq ? Q  : K;
    const float* W  = isq ? Wq : Wk;
    const int r0 = (isq ? blk : blk - NQBLK) * 4;
    const int t  = threadIdx.x;

    float acc0 = 0.f, acc1 = 0.f, acc2 = 0.f, acc3 = 0.f;
    const float4* in4 = reinterpret_cast<const float4*>(in + (size_t)r0 * DQK_);
    for (int d4 = 0; d4 < DQK_ / 4; ++d4) {
        float4 r0v = in4[0 * (DQK_ / 4) + d4];   // uniform -> s_load
        float4 r1v = in4[1 * (DQK_ / 4) + d4];
        float4 r2v = in4[2 * (DQK_ / 4) + d4];
        float4 r3v = in4[3 * (DQK_ / 4) + d4];
#pragma unroll
        for (int e = 0; e < 4; ++e) {
            float w = W[(size_t)(4 * d4 + e) * H_ + t];   // coalesced
            acc0 = fmaf(reinterpret_cast<const float*>(&r0v)[e], w, acc0);
            acc1 = fmaf(reinterpret_cast<const float*>(&r1v)[e], w, acc1);
            acc2 = fmaf(reinterpret_cast<const float*>(&r2v)[e], w, acc2);
            acc3 = fmaf(reinterpret_cast<const float*>(&r3v)[e], w, acc3);
        }
    }
    float e0 = __builtin_amdgcn_exp2f(acc0 * TANH_C);
    float e1 = __builtin_amdgcn_exp2f(acc1 * TANH_C);
    float e2 = __builtin_amdgcn_exp2f(acc2 * TANH_C);
    float e3 = __builtin_amdgcn_exp2f(acc3 * TANH_C);
    if (isq) {
        eq[(size_t)(r0 + 0) * H_ + t] = e0;
        eq[(size_t)(r0 + 1) * H_ + t] = e1;
        eq[(size_t)(r0 + 2) * H_ + t] = e2;
        eq[(size_t)(r0 + 3) * H_ + t] = e3;
    } else {
        const int b  = r0 >> 9;
        const int k0 = r0 & (LK_ - 1);
        float* o = ekT + ((size_t)(b * H_ + t)) * LK_ + k0;
        *reinterpret_cast<float4*>(o) = make_float4(e0, e1, e2, e3);
    }
}

// ---------------------------------------------------------------------------
// attn_kernel_x4: R9 attn kernel with the body executed REP_ times.
// Each rep recomputes identical values and rewrites the same output ->
// deterministic, validation-safe. Counters (ratios) reflect the real kernel.
// ---------------------------------------------------------------------------
__global__ __launch_bounds__(1024) void attn_kernel_x4(
    const float* __restrict__ eq,          // [B*LQ, H]
    const float* __restrict__ ekT,         // [B, H, LK]
    const float* __restrict__ wv,          // [H]
    const float* __restrict__ values,      // [B, LK, DV]
    const int*   __restrict__ valid_lens,  // [B]
    float* __restrict__ out) {             // [B*LQ, DV]
    __shared__ float eq_l[4][H_];          // 2 KB
    __shared__ float wm2[H_];              // 512 B
    __shared__ float sc[LK_][4];           // 8 KB (e-values, [k][row])
    __shared__ float scratch[8 * 128 * 20];// 80 KB: partB then partD
    __shared__ float red[16];
    __shared__ float inv_s[4];

    float (*partB)[128][20] = reinterpret_cast<float (*)[128][20]>(scratch);
    float (*partD)[4][DV_]  = reinterpret_cast<float (*)[4][DV_]>(scratch);

    const int blk = blockIdx.x;            // b*64 + qt
    const int b   = blk >> 6;
    const int qt  = blk & 63;
    const int t   = threadIdx.x;

    if (t < 512) {
        eq_l[t >> 7][t & 127] = eq[(size_t)(b * LQ_ + qt * 4 + (t >> 7)) * H_ + (t & 127)];
    } else if (t < 640) {
        wm2[t - 512] = -2.f * wv[t - 512];
    }
    __syncthreads();

    const int valid = valid_lens[b];

    for (int rep = 0; rep < REP_; ++rep) {

    // ---- Phase B: register-blocked partial scores ----
    {
        const int quad = t & 127;          // k-quad: k = 4*quad + e
        const int hs   = t >> 7;           // h-slice: h = 16*hs + hh
        const int k0   = 4 * quad;
        float acc[16];
#pragma unroll
        for (int i = 0; i < 16; ++i) acc[i] = 0.f;

        if (k0 < valid) {
            const float* ekb = ekT + (size_t)b * H_ * LK_ + k0;
#pragma unroll 2
            for (int hh = 0; hh < 16; ++hh) {
                const int h = 16 * hs + hh;
                float4 ek = *reinterpret_cast<const float4*>(ekb + (size_t)h * LK_);
                float w = wm2[h];          // LDS broadcast
#pragma unroll
                for (int r = 0; r < 4; ++r) {
                    float qv = eq_l[r][h]; // LDS broadcast
                    acc[4 * r + 0] = fmaf(w, __builtin_amdgcn_rcpf(fmaf(qv, ek.x, 1.f)), acc[4 * r + 0]);
                    acc[4 * r + 1] = fmaf(w, __builtin_amdgcn_rcpf(fmaf(qv, ek.y, 1.f)), acc[4 * r + 1]);
                    acc[4 * r + 2] = fmaf(w, __builtin_amdgcn_rcpf(fmaf(qv, ek.z, 1.f)), acc[4 * r + 2]);
                    acc[4 * r + 3] = fmaf(w, __builtin_amdgcn_rcpf(fmaf(qv, ek.w, 1.f)), acc[4 * r + 3]);
                }
            }
        }
        float* pb = &partB[hs][quad][0];
#pragma unroll
        for (int i = 0; i < 4; ++i)
            *reinterpret_cast<float4*>(pb + 4 * i) = *reinterpret_cast<float4*>(&acc[4 * i]);
    }
    __syncthreads();

    // ---- Score stage: reduce 8 h-slices, exp2, mask -> sc[k][r] ----
#pragma unroll
    for (int j = 0; j < 2; ++j) {
        const int o    = t + 1024 * j;     // 0..2047
        const int quad = o >> 4;
        const int idx  = o & 15;           // r*4 + e
        const int k    = 4 * quad + (idx & 3);
        float s = 0.f;
#pragma unroll
        for (int hs = 0; hs < 8; ++hs) s += partB[hs][quad][idx];
        sc[k][idx >> 2] = (k < valid) ? __builtin_amdgcn_exp2f(s * L2E) : 0.f;
    }
    __syncthreads();

    // ---- Phase C: per-row sum only (wave w -> row qi = w>>2) ----
    const int qi = t >> 8;                 // 0..3 wave-uniform
    const int kl = t & 255;
    {
        float ss = sc[kl][qi] + sc[kl + 256][qi];
#pragma unroll
        for (int off = 32; off; off >>= 1) ss += __shfl_down(ss, off, 64);
        if ((t & 63) == 0) red[t >> 6] = ss;
    }
    __syncthreads();
    if (t < 4) {
        inv_s[t] = 1.f / (red[4 * t] + red[4 * t + 1] + red[4 * t + 2] + red[4 * t + 3]);
    }
    __syncthreads();                        // also fences partB before partD reuse

    // ---- Phase D: out = attn @ values (float4 values, wave-per-k-slice) ----
    {
        const int w  = __builtin_amdgcn_readfirstlane(t >> 6);  // wave 0..15
        const int v  = 4 * (t & 63);
        const int kstart = 32 * w;
        const int kend   = min(kstart + 32, valid);
        const float* vb = values + (size_t)b * LK_ * DV_ + v;
        float4 a0 = make_float4(0.f, 0.f, 0.f, 0.f);
        float4 a1 = a0, a2 = a0, a3 = a0;
#pragma unroll 2
        for (int k = kstart; k < kend; ++k) {
            float4 sv = *reinterpret_cast<const float4*>(&sc[k][0]);     // broadcast
            float4 vv = *reinterpret_cast<const float4*>(vb + (size_t)k * DV_); // coalesced
            a0.x = fmaf(sv.x, vv.x, a0.x); a0.y = fmaf(sv.x, vv.y, a0.y);
            a0.z = fmaf(sv.x, vv.z, a0.z); a0.w = fmaf(sv.x, vv.w, a0.w);
            a1.x = fmaf(sv.y, vv.x, a1.x); a1.y = fmaf(sv.y, vv.y, a1.y);
            a1.z = fmaf(sv.y, vv.z, a1.z); a1.w = fmaf(sv.y, vv.w, a1.w);
            a2.x = fmaf(sv.z, vv.x, a2.x); a2.y = fmaf(sv.z, vv.y, a2.y);
            a2.z = fmaf(sv.z, vv.z, a2.z); a2.w = fmaf(sv.z, vv.w, a2.w);
            a3.x = fmaf(sv.w, vv.x, a3.x); a3.y = fmaf(sv.w, vv.y, a3.y);
            a3.z = fmaf(sv.w, vv.z, a3.z); a3.w = fmaf(sv.w, vv.w, a3.w);
        }
        *reinterpret_cast<float4*>(&partD[w][0][v]) = a0;
        *reinterpret_cast<float4*>(&partD[w][1][v]) = a1;
        *reinterpret_cast<float4*>(&partD[w][2][v]) = a2;
        *reinterpret_cast<float4*>(&partD[w][3][v]) = a3;
    }
    __syncthreads();
    {
        const int r = t >> 8;
        const int v = t & 255;
        float s = 0.f;
#pragma unroll
        for (int w = 0; w < 16; ++w) s += partD[w][r][v];
        out[(size_t)(b * LQ_ + qt * 4 + r) * DV_ + v] = s * inv_s[r];
    }
    __syncthreads();                        // fence before next rep reuses scratch

    } // rep
}

extern "C" void kernel_launch(void* const* d_in, const int* in_sizes, int n_in,
                              void* d_out, int out_size, void* d_ws, size_t ws_size,
                              hipStream_t stream) {
    const float* queries    = (const float*)d_in[0];  // [B, LQ, DQ]
    const float* keys       = (const float*)d_in[1];  // [B, LK, DK]
    const float* values     = (const float*)d_in[2];  // [B, LK, DV]
    const float* Wq         = (const float*)d_in[3];  // [DQ, H]
    const float* Wk         = (const float*)d_in[4];  // [DK, H]
    const float* wv         = (const float*)d_in[5];  // [H]
    const int*   valid_lens = (const int*)d_in[6];    // [B]
    float* out = (float*)d_out;

    float* eq  = (float*)d_ws;                   // [B*LQ, H]   512 KB
    float* ekT = eq + (size_t)B_ * LQ_ * H_;     // [B, H, LK]  1 MB

    proj_kernel<<<NQBLK + NKBLK, 128, 0, stream>>>(queries, keys, Wq, Wk, eq, ekT);
    attn_kernel_x4<<<B_ * LQ_ / 4, 1024, 0, stream>>>(eq, ekT, wv, values, valid_lens, out);
}

// Round 11
// 29.546 us; speedup vs baseline: 2.2018x; 2.2018x over previous
//
#include <hip/hip_runtime.h>

// B=4, LQ=256, LK=512, DQ=DK=DV=256, H=128
#define B_   4
#define LQ_  256
#define LK_  512
#define DQK_ 256
#define DV_  256
#define H_   128

#define TANH_C 2.8853900817779268f   // 2*log2(e): tanh(x) = 1 - 2/(exp2(TANH_C*x)+1)
#define L2E    1.4426950408889634f
#define NQBLK (B_ * LQ_ / 4)         // 256 q-proj blocks (TILE=4)
#define NKBLK (B_ * LK_ / 4)         // 512 k-proj blocks

// R10 findings (attn_x4 counters): warm attn rep ~12us, cold excess ~10-13us
// = first-touch of ekT(64MB)+values(128MB) re-reads through L3/remote L2.
// R11 change: XCD-affinity swizzle -- batch b's blocks pinned to XCD pair
// {2b,2b+1} (assuming XCD = blockIdx % 8 round-robin) so values[b]+ekT[b]
// live in one local L2 (768 KB << 4 MB) after one L3 fetch per XCD.

// ---------------------------------------------------------------------------
// proj_kernel: fused q+k projection. TILE=4, 128 thr. k-part XCD-swizzled so
// ekT[b] is written into the same XCD L2 that attn batch-b blocks will read.
// ---------------------------------------------------------------------------
__global__ __launch_bounds__(128) void proj_kernel(const float* __restrict__ Q,
                                                   const float* __restrict__ K,
                                                   const float* __restrict__ Wq,
                                                   const float* __restrict__ Wk,
                                                   float* __restrict__ eq,
                                                   float* __restrict__ ekT) {
    const int blk = blockIdx.x;
    const bool isq = blk < NQBLK;
    const float* in = isq ? Q  : K;
    const float* W  = isq ? Wq : Wk;
    int r0;
    if (isq) {
        r0 = blk * 4;
    } else {
        // k-part: physical XCD = blk % 8 = (blk-NQBLK) % 8 (NQBLK % 8 == 0).
        const int i   = blk - NQBLK;       // 0..511
        const int xcd = i & 7;
        const int b   = xcd >> 1;          // batch pinned to XCD pair {2b,2b+1}
        const int j   = ((i >> 3) << 1) | (i & 1);   // 0..127 within batch
        r0 = b * LK_ + j * 4;
    }
    const int t  = threadIdx.x;

    float acc0 = 0.f, acc1 = 0.f, acc2 = 0.f, acc3 = 0.f;
    const float4* in4 = reinterpret_cast<const float4*>(in + (size_t)r0 * DQK_);
    for (int d4 = 0; d4 < DQK_ / 4; ++d4) {
        float4 r0v = in4[0 * (DQK_ / 4) + d4];   // uniform -> s_load
        float4 r1v = in4[1 * (DQK_ / 4) + d4];
        float4 r2v = in4[2 * (DQK_ / 4) + d4];
        float4 r3v = in4[3 * (DQK_ / 4) + d4];
#pragma unroll
        for (int e = 0; e < 4; ++e) {
            float w = W[(size_t)(4 * d4 + e) * H_ + t];   // coalesced
            acc0 = fmaf(reinterpret_cast<const float*>(&r0v)[e], w, acc0);
            acc1 = fmaf(reinterpret_cast<const float*>(&r1v)[e], w, acc1);
            acc2 = fmaf(reinterpret_cast<const float*>(&r2v)[e], w, acc2);
            acc3 = fmaf(reinterpret_cast<const float*>(&r3v)[e], w, acc3);
        }
    }
    float e0 = __builtin_amdgcn_exp2f(acc0 * TANH_C);
    float e1 = __builtin_amdgcn_exp2f(acc1 * TANH_C);
    float e2 = __builtin_amdgcn_exp2f(acc2 * TANH_C);
    float e3 = __builtin_amdgcn_exp2f(acc3 * TANH_C);
    if (isq) {
        eq[(size_t)(r0 + 0) * H_ + t] = e0;
        eq[(size_t)(r0 + 1) * H_ + t] = e1;
        eq[(size_t)(r0 + 2) * H_ + t] = e2;
        eq[(size_t)(r0 + 3) * H_ + t] = e3;
    } else {
        const int b  = r0 >> 9;
        const int k0 = r0 & (LK_ - 1);
        float* o = ekT + ((size_t)(b * H_ + t)) * LK_ + k0;
        *reinterpret_cast<float4*>(o) = make_float4(e0, e1, e2, e3);
    }
}

// ---------------------------------------------------------------------------
// attn_kernel (R9 body, XCD-swizzled block mapping): one block per (b, qtile
// of 4), 1024 threads (16 waves).
//   xcd = blk&7 -> b = xcd>>1 (batch pinned to XCD pair), qt from parity+slot.
// ---------------------------------------------------------------------------
__global__ __launch_bounds__(1024) void attn_kernel(
    const float* __restrict__ eq,          // [B*LQ, H]
    const float* __restrict__ ekT,         // [B, H, LK]
    const float* __restrict__ wv,          // [H]
    const float* __restrict__ values,      // [B, LK, DV]
    const int*   __restrict__ valid_lens,  // [B]
    float* __restrict__ out) {             // [B*LQ, DV]
    __shared__ float eq_l[4][H_];          // 2 KB
    __shared__ float wm2[H_];              // 512 B
    __shared__ float sc[LK_][4];           // 8 KB (e-values, [k][row])
    __shared__ float scratch[8 * 128 * 20];// 80 KB: partB then partD
    __shared__ float red[16];
    __shared__ float inv_s[4];

    float (*partB)[128][20] = reinterpret_cast<float (*)[128][20]>(scratch);
    float (*partD)[4][DV_]  = reinterpret_cast<float (*)[4][DV_]>(scratch);

    const int blk = blockIdx.x;            // 0..255
    const int xcd = blk & 7;               // assumed physical XCD (round-robin)
    const int b   = xcd >> 1;              // batch pinned to XCD pair {2b,2b+1}
    const int qt  = ((xcd & 1) << 5) | (blk >> 3);   // 0..63
    const int t   = threadIdx.x;

    if (t < 512) {
        eq_l[t >> 7][t & 127] = eq[(size_t)(b * LQ_ + qt * 4 + (t >> 7)) * H_ + (t & 127)];
    } else if (t < 640) {
        wm2[t - 512] = -2.f * wv[t - 512];
    }
    __syncthreads();

    const int valid = valid_lens[b];

    // ---- Phase B: register-blocked partial scores ----
    {
        const int quad = t & 127;          // k-quad: k = 4*quad + e
        const int hs   = t >> 7;           // h-slice: h = 16*hs + hh
        const int k0   = 4 * quad;
        float acc[16];
#pragma unroll
        for (int i = 0; i < 16; ++i) acc[i] = 0.f;

        if (k0 < valid) {
            const float* ekb = ekT + (size_t)b * H_ * LK_ + k0;
#pragma unroll 2
            for (int hh = 0; hh < 16; ++hh) {
                const int h = 16 * hs + hh;
                float4 ek = *reinterpret_cast<const float4*>(ekb + (size_t)h * LK_);
                float w = wm2[h];          // LDS broadcast
#pragma unroll
                for (int r = 0; r < 4; ++r) {
                    float qv = eq_l[r][h]; // LDS broadcast
                    acc[4 * r + 0] = fmaf(w, __builtin_amdgcn_rcpf(fmaf(qv, ek.x, 1.f)), acc[4 * r + 0]);
                    acc[4 * r + 1] = fmaf(w, __builtin_amdgcn_rcpf(fmaf(qv, ek.y, 1.f)), acc[4 * r + 1]);
                    acc[4 * r + 2] = fmaf(w, __builtin_amdgcn_rcpf(fmaf(qv, ek.z, 1.f)), acc[4 * r + 2]);
                    acc[4 * r + 3] = fmaf(w, __builtin_amdgcn_rcpf(fmaf(qv, ek.w, 1.f)), acc[4 * r + 3]);
                }
            }
        }
        float* pb = &partB[hs][quad][0];
#pragma unroll
        for (int i = 0; i < 4; ++i)
            *reinterpret_cast<float4*>(pb + 4 * i) = *reinterpret_cast<float4*>(&acc[4 * i]);
    }
    __syncthreads();

    // ---- Score stage: reduce 8 h-slices, exp2, mask -> sc[k][r] ----
#pragma unroll
    for (int j = 0; j < 2; ++j) {
        const int o    = t + 1024 * j;     // 0..2047
        const int quad = o >> 4;
        const int idx  = o & 15;           // r*4 + e
        const int k    = 4 * quad + (idx & 3);
        float s = 0.f;
#pragma unroll
        for (int hs = 0; hs < 8; ++hs) s += partB[hs][quad][idx];
        sc[k][idx >> 2] = (k < valid) ? __builtin_amdgcn_exp2f(s * L2E) : 0.f;
    }
    __syncthreads();

    // ---- Phase C: per-row sum only (wave w -> row qi = w>>2) ----
    const int qi = t >> 8;                 // 0..3 wave-uniform
    const int kl = t & 255;
    {
        float ss = sc[kl][qi] + sc[kl + 256][qi];
#pragma unroll
        for (int off = 32; off; off >>= 1) ss += __shfl_down(ss, off, 64);
        if ((t & 63) == 0) red[t >> 6] = ss;
    }
    __syncthreads();
    if (t < 4) {
        inv_s[t] = 1.f / (red[4 * t] + red[4 * t + 1] + red[4 * t + 2] + red[4 * t + 3]);
    }
    __syncthreads();                        // also fences partB before partD reuse

    // ---- Phase D: out = attn @ values (float4 values, wave-per-k-slice) ----
    {
        const int w  = __builtin_amdgcn_readfirstlane(t >> 6);  // wave 0..15
        const int v  = 4 * (t & 63);
        const int kstart = 32 * w;
        const int kend   = min(kstart + 32, valid);
        const float* vb = values + (size_t)b * LK_ * DV_ + v;
        float4 a0 = make_float4(0.f, 0.f, 0.f, 0.f);
        float4 a1 = a0, a2 = a0, a3 = a0;
#pragma unroll 2
        for (int k = kstart; k < kend; ++k) {
            float4 sv = *reinterpret_cast<const float4*>(&sc[k][0]);     // broadcast
            float4 vv = *reinterpret_cast<const float4*>(vb + (size_t)k * DV_); // coalesced
            a0.x = fmaf(sv.x, vv.x, a0.x); a0.y = fmaf(sv.x, vv.y, a0.y);
            a0.z = fmaf(sv.x, vv.z, a0.z); a0.w = fmaf(sv.x, vv.w, a0.w);
            a1.x = fmaf(sv.y, vv.x, a1.x); a1.y = fmaf(sv.y, vv.y, a1.y);
            a1.z = fmaf(sv.y, vv.z, a1.z); a1.w = fmaf(sv.y, vv.w, a1.w);
            a2.x = fmaf(sv.z, vv.x, a2.x); a2.y = fmaf(sv.z, vv.y, a2.y);
            a2.z = fmaf(sv.z, vv.z, a2.z); a2.w = fmaf(sv.z, vv.w, a2.w);
            a3.x = fmaf(sv.w, vv.x, a3.x); a3.y = fmaf(sv.w, vv.y, a3.y);
            a3.z = fmaf(sv.w, vv.z, a3.z); a3.w = fmaf(sv.w, vv.w, a3.w);
        }
        *reinterpret_cast<float4*>(&partD[w][0][v]) = a0;
        *reinterpret_cast<float4*>(&partD[w][1][v]) = a1;
        *reinterpret_cast<float4*>(&partD[w][2][v]) = a2;
        *reinterpret_cast<float4*>(&partD[w][3][v]) = a3;
    }
    __syncthreads();
    {
        const int r = t >> 8;
        const int v = t & 255;
        float s = 0.f;
#pragma unroll
        for (int w = 0; w < 16; ++w) s += partD[w][r][v];
        out[(size_t)(b * LQ_ + qt * 4 + r) * DV_ + v] = s * inv_s[r];
    }
}

extern "C" void kernel_launch(void* const* d_in, const int* in_sizes, int n_in,
                              void* d_out, int out_size, void* d_ws, size_t ws_size,
                              hipStream_t stream) {
    const float* queries    = (const float*)d_in[0];  // [B, LQ, DQ]
    const float* keys       = (const float*)d_in[1];  // [B, LK, DK]
    const float* values     = (const float*)d_in[2];  // [B, LK, DV]
    const float* Wq         = (const float*)d_in[3];  // [DQ, H]
    const float* Wk         = (const float*)d_in[4];  // [DK, H]
    const float* wv         = (const float*)d_in[5];  // [H]
    const int*   valid_lens = (const int*)d_in[6];    // [B]
    float* out = (float*)d_out;

    float* eq  = (float*)d_ws;                   // [B*LQ, H]   512 KB
    float* ekT = eq + (size_t)B_ * LQ_ * H_;     // [B, H, LK]  1 MB

    proj_kernel<<<NQBLK + NKBLK, 128, 0, stream>>>(queries, keys, Wq, Wk, eq, ekT);
    attn_kernel<<<B_ * LQ_ / 4, 1024, 0, stream>>>(eq, ekT, wv, values, valid_lens, out);
}

// Round 13
// 29.236 us; speedup vs baseline: 2.2252x; 1.0106x over previous
//
#include <hip/hip_runtime.h>

// B=4, LQ=256, LK=512, DQ=DK=DV=256, H=128
#define B_   4
#define LQ_  256
#define LK_  512
#define DQK_ 256
#define DV_  256
#define H_   128

#define TANH_C 2.8853900817779268f   // 2*log2(e): tanh(x) = 1 - 2/(exp2(TANH_C*x)+1)
#define L2E    1.4426950408889634f
#define NQBLK (B_ * LQ_ / 4)         // 256 q-proj blocks (TILE=4)
#define NKBLK (B_ * LK_ / 4)         // 512 k-proj blocks

typedef float vfloat4 __attribute__((ext_vector_type(4)));  // NT-store-compatible

// R10 measured: warm attn rep ~12us, cold rep ~25us. R11 (XCD swizzle) neutral.
// R12/13 theory: cold excess = cross-XCD DIRTY-line reads of ekT/eq (rewritten
// by proj every replay). Fix: non-temporal stores in proj -> lines evicted
// toward L3 clean; readers fetch at L3 BW without coherence stalls.
// attn body = R9 bit-exact.

// ---------------------------------------------------------------------------
// proj_kernel (R4 structure + NT stores): fused q+k projection. TILE=4.
// ---------------------------------------------------------------------------
__global__ __launch_bounds__(128) void proj_kernel(const float* __restrict__ Q,
                                                   const float* __restrict__ K,
                                                   const float* __restrict__ Wq,
                                                   const float* __restrict__ Wk,
                                                   float* __restrict__ eq,
                                                   float* __restrict__ ekT) {
    const int blk = blockIdx.x;
    const bool isq = blk < NQBLK;
    const float* in = isq ? Q  : K;
    const float* W  = isq ? Wq : Wk;
    const int r0 = (isq ? blk : blk - NQBLK) * 4;
    const int t  = threadIdx.x;

    float acc0 = 0.f, acc1 = 0.f, acc2 = 0.f, acc3 = 0.f;
    const float4* in4 = reinterpret_cast<const float4*>(in + (size_t)r0 * DQK_);
    for (int d4 = 0; d4 < DQK_ / 4; ++d4) {
        float4 r0v = in4[0 * (DQK_ / 4) + d4];   // uniform -> s_load
        float4 r1v = in4[1 * (DQK_ / 4) + d4];
        float4 r2v = in4[2 * (DQK_ / 4) + d4];
        float4 r3v = in4[3 * (DQK_ / 4) + d4];
#pragma unroll
        for (int e = 0; e < 4; ++e) {
            float w = W[(size_t)(4 * d4 + e) * H_ + t];   // coalesced
            acc0 = fmaf(reinterpret_cast<const float*>(&r0v)[e], w, acc0);
            acc1 = fmaf(reinterpret_cast<const float*>(&r1v)[e], w, acc1);
            acc2 = fmaf(reinterpret_cast<const float*>(&r2v)[e], w, acc2);
            acc3 = fmaf(reinterpret_cast<const float*>(&r3v)[e], w, acc3);
        }
    }
    float e0 = __builtin_amdgcn_exp2f(acc0 * TANH_C);
    float e1 = __builtin_amdgcn_exp2f(acc1 * TANH_C);
    float e2 = __builtin_amdgcn_exp2f(acc2 * TANH_C);
    float e3 = __builtin_amdgcn_exp2f(acc3 * TANH_C);
    if (isq) {
        __builtin_nontemporal_store(e0, &eq[(size_t)(r0 + 0) * H_ + t]);
        __builtin_nontemporal_store(e1, &eq[(size_t)(r0 + 1) * H_ + t]);
        __builtin_nontemporal_store(e2, &eq[(size_t)(r0 + 2) * H_ + t]);
        __builtin_nontemporal_store(e3, &eq[(size_t)(r0 + 3) * H_ + t]);
    } else {
        const int b  = r0 >> 9;
        const int k0 = r0 & (LK_ - 1);
        float* o = ekT + ((size_t)(b * H_ + t)) * LK_ + k0;
        vfloat4 v4 = {e0, e1, e2, e3};
        __builtin_nontemporal_store(v4, reinterpret_cast<vfloat4*>(o));
    }
}

// ---------------------------------------------------------------------------
// attn_kernel (R9 bit-exact): one block per (b, q-tile of 4), 1024 threads.
// ---------------------------------------------------------------------------
__global__ __launch_bounds__(1024) void attn_kernel(
    const float* __restrict__ eq,          // [B*LQ, H]
    const float* __restrict__ ekT,         // [B, H, LK]
    const float* __restrict__ wv,          // [H]
    const float* __restrict__ values,      // [B, LK, DV]
    const int*   __restrict__ valid_lens,  // [B]
    float* __restrict__ out) {             // [B*LQ, DV]
    __shared__ float eq_l[4][H_];          // 2 KB
    __shared__ float wm2[H_];              // 512 B
    __shared__ float sc[LK_][4];           // 8 KB (e-values, [k][row])
    __shared__ float scratch[8 * 128 * 20];// 80 KB: partB then partD
    __shared__ float red[16];
    __shared__ float inv_s[4];

    float (*partB)[128][20] = reinterpret_cast<float (*)[128][20]>(scratch);
    float (*partD)[4][DV_]  = reinterpret_cast<float (*)[4][DV_]>(scratch);

    const int blk = blockIdx.x;            // b*64 + qt
    const int b   = blk >> 6;
    const int qt  = blk & 63;
    const int t   = threadIdx.x;

    if (t < 512) {
        eq_l[t >> 7][t & 127] = eq[(size_t)(b * LQ_ + qt * 4 + (t >> 7)) * H_ + (t & 127)];
    } else if (t < 640) {
        wm2[t - 512] = -2.f * wv[t - 512];
    }
    __syncthreads();

    const int valid = valid_lens[b];

    // ---- Phase B: register-blocked partial scores ----
    {
        const int quad = t & 127;          // k-quad: k = 4*quad + e
        const int hs   = t >> 7;           // h-slice: h = 16*hs + hh
        const int k0   = 4 * quad;
        float acc[16];
#pragma unroll
        for (int i = 0; i < 16; ++i) acc[i] = 0.f;

        if (k0 < valid) {
            const float* ekb = ekT + (size_t)b * H_ * LK_ + k0;
#pragma unroll 2
            for (int hh = 0; hh < 16; ++hh) {
                const int h = 16 * hs + hh;
                float4 ek = *reinterpret_cast<const float4*>(ekb + (size_t)h * LK_);
                float w = wm2[h];          // LDS broadcast
#pragma unroll
                for (int r = 0; r < 4; ++r) {
                    float qv = eq_l[r][h]; // LDS broadcast
                    acc[4 * r + 0] = fmaf(w, __builtin_amdgcn_rcpf(fmaf(qv, ek.x, 1.f)), acc[4 * r + 0]);
                    acc[4 * r + 1] = fmaf(w, __builtin_amdgcn_rcpf(fmaf(qv, ek.y, 1.f)), acc[4 * r + 1]);
                    acc[4 * r + 2] = fmaf(w, __builtin_amdgcn_rcpf(fmaf(qv, ek.z, 1.f)), acc[4 * r + 2]);
                    acc[4 * r + 3] = fmaf(w, __builtin_amdgcn_rcpf(fmaf(qv, ek.w, 1.f)), acc[4 * r + 3]);
                }
            }
        }
        float* pb = &partB[hs][quad][0];
#pragma unroll
        for (int i = 0; i < 4; ++i)
            *reinterpret_cast<float4*>(pb + 4 * i) = *reinterpret_cast<float4*>(&acc[4 * i]);
    }
    __syncthreads();

    // ---- Score stage: reduce 8 h-slices, exp2, mask -> sc[k][r] ----
#pragma unroll
    for (int j = 0; j < 2; ++j) {
        const int o    = t + 1024 * j;     // 0..2047
        const int quad = o >> 4;
        const int idx  = o & 15;           // r*4 + e
        const int k    = 4 * quad + (idx & 3);
        float s = 0.f;
#pragma unroll
        for (int hs = 0; hs < 8; ++hs) s += partB[hs][quad][idx];
        sc[k][idx >> 2] = (k < valid) ? __builtin_amdgcn_exp2f(s * L2E) : 0.f;
    }
    __syncthreads();

    // ---- Phase C: per-row sum only (wave w -> row qi = w>>2) ----
    const int qi = t >> 8;                 // 0..3 wave-uniform
    const int kl = t & 255;
    {
        float ss = sc[kl][qi] + sc[kl + 256][qi];
#pragma unroll
        for (int off = 32; off; off >>= 1) ss += __shfl_down(ss, off, 64);
        if ((t & 63) == 0) red[t >> 6] = ss;
    }
    __syncthreads();
    if (t < 4) {
        inv_s[t] = 1.f / (red[4 * t] + red[4 * t + 1] + red[4 * t + 2] + red[4 * t + 3]);
    }
    __syncthreads();                        // also fences partB before partD reuse

    // ---- Phase D: out = attn @ values (float4 values, wave-per-k-slice) ----
    {
        const int w  = __builtin_amdgcn_readfirstlane(t >> 6);  // wave 0..15
        const int v  = 4 * (t & 63);
        const int kstart = 32 * w;
        const int kend   = min(kstart + 32, valid);
        const float* vb = values + (size_t)b * LK_ * DV_ + v;
        float4 a0 = make_float4(0.f, 0.f, 0.f, 0.f);
        float4 a1 = a0, a2 = a0, a3 = a0;
#pragma unroll 2
        for (int k = kstart; k < kend; ++k) {
            float4 sv = *reinterpret_cast<const float4*>(&sc[k][0]);     // broadcast
            float4 vv = *reinterpret_cast<const float4*>(vb + (size_t)k * DV_); // coalesced
            a0.x = fmaf(sv.x, vv.x, a0.x); a0.y = fmaf(sv.x, vv.y, a0.y);
            a0.z = fmaf(sv.x, vv.z, a0.z); a0.w = fmaf(sv.x, vv.w, a0.w);
            a1.x = fmaf(sv.y, vv.x, a1.x); a1.y = fmaf(sv.y, vv.y, a1.y);
            a1.z = fmaf(sv.y, vv.z, a1.z); a1.w = fmaf(sv.y, vv.w, a1.w);
            a2.x = fmaf(sv.z, vv.x, a2.x); a2.y = fmaf(sv.z, vv.y, a2.y);
            a2.z = fmaf(sv.z, vv.z, a2.z); a2.w = fmaf(sv.z, vv.w, a2.w);
            a3.x = fmaf(sv.w, vv.x, a3.x); a3.y = fmaf(sv.w, vv.y, a3.y);
            a3.z = fmaf(sv.w, vv.z, a3.z); a3.w = fmaf(sv.w, vv.w, a3.w);
        }
        *reinterpret_cast<float4*>(&partD[w][0][v]) = a0;
        *reinterpret_cast<float4*>(&partD[w][1][v]) = a1;
        *reinterpret_cast<float4*>(&partD[w][2][v]) = a2;
        *reinterpret_cast<float4*>(&partD[w][3][v]) = a3;
    }
    __syncthreads();
    {
        const int r = t >> 8;
        const int v = t & 255;
        float s = 0.f;
#pragma unroll
        for (int w = 0; w < 16; ++w) s += partD[w][r][v];
        out[(size_t)(b * LQ_ + qt * 4 + r) * DV_ + v] = s * inv_s[r];
    }
}

extern "C" void kernel_launch(void* const* d_in, const int* in_sizes, int n_in,
                              void* d_out, int out_size, void* d_ws, size_t ws_size,
                              hipStream_t stream) {
    const float* queries    = (const float*)d_in[0];  // [B, LQ, DQ]
    const float* keys       = (const float*)d_in[1];  // [B, LK, DK]
    const float* values     = (const float*)d_in[2];  // [B, LK, DV]
    const float* Wq         = (const float*)d_in[3];  // [DQ, H]
    const float* Wk         = (const float*)d_in[4];  // [DK, H]
    const float* wv         = (const float*)d_in[5];  // [H]
    const int*   valid_lens = (const int*)d_in[6];    // [B]
    float* out = (float*)d_out;

    float* eq  = (float*)d_ws;                   // [B*LQ, H]   512 KB
    float* ekT = eq + (size_t)B_ * LQ_ * H_;     // [B, H, LK]  1 MB

    proj_kernel<<<NQBLK + NKBLK, 128, 0, stream>>>(queries, keys, Wq, Wk, eq, ekT);
    attn_kernel<<<B_ * LQ_ / 4, 1024, 0, stream>>>(eq, ekT, wv, values, valid_lens, out);
}

// Round 15
// 29.176 us; speedup vs baseline: 2.2297x; 1.0020x over previous
//
#include <hip/hip_runtime.h>

// B=4, LQ=256, LK=512, DQ=DK=DV=256, H=128
#define B_   4
#define LQ_  256
#define LK_  512
#define DQK_ 256
#define DV_  256
#define H_   128

#define TANH_C 2.8853900817779268f   // 2*log2(e): tanh(x) = 1 - 2/(exp2(TANH_C*x)+1)
#define L2E    1.4426950408889634f
#define NQBLK (B_ * LQ_ / 4)         // 256 q-proj blocks (TILE=4)
#define NKBLK (B_ * LK_ / 4)         // 512 k-proj blocks
#define NPREF 64                     // values-prefetch blocks appended to proj

// R14 theory (retry; R14 crashed on an OOB prefetch read — 4x overrun, fixed):
// cold excess = 64-way DUPLICATED cold misses (all blocks of a batch stream
// identical ekT/values lines in the same order into a cache swept by the
// harness's 268MB ws re-poison fill). Fix: (1) stagger per-block traversal
// order, (2) prefetch values into L2/L3 during proj via 64 reader blocks.

// ---------------------------------------------------------------------------
// proj_kernel: fused q+k projection (R4 core) + values prefetch tail blocks.
// ---------------------------------------------------------------------------
__global__ __launch_bounds__(128) void proj_kernel(const float* __restrict__ Q,
                                                   const float* __restrict__ K,
                                                   const float* __restrict__ Wq,
                                                   const float* __restrict__ Wk,
                                                   const float* __restrict__ values,
                                                   float* __restrict__ eq,
                                                   float* __restrict__ ekT,
                                                   float* __restrict__ dummy) {
    const int blk = blockIdx.x;
    const int t   = threadIdx.x;

    if (blk >= NQBLK + NKBLK) {
        // ---- values prefetch: 131072 float4 total = 64 blocks x 16 x 128 ----
        const int j = blk - (NQBLK + NKBLK);           // 0..63
        const float4* v4 = reinterpret_cast<const float4*>(values);
        float4 s = make_float4(0.f, 0.f, 0.f, 0.f);
#pragma unroll 4
        for (int i = 0; i < 16; ++i) {
            float4 x = v4[(size_t)j * 2048 + i * 128 + t];   // coalesced, in-bounds
            s.x += x.x; s.y += x.y; s.z += x.z; s.w += x.w;
        }
        if (t == 0) dummy[j] = s.x + s.y + s.z + s.w;  // dead ws slot, deterministic
        return;
    }

    const bool isq = blk < NQBLK;
    const float* in = isq ? Q  : K;
    const float* W  = isq ? Wq : Wk;
    const int r0 = (isq ? blk : blk - NQBLK) * 4;

    float acc0 = 0.f, acc1 = 0.f, acc2 = 0.f, acc3 = 0.f;
    const float4* in4 = reinterpret_cast<const float4*>(in + (size_t)r0 * DQK_);
    for (int d4 = 0; d4 < DQK_ / 4; ++d4) {
        float4 r0v = in4[0 * (DQK_ / 4) + d4];   // uniform -> s_load
        float4 r1v = in4[1 * (DQK_ / 4) + d4];
        float4 r2v = in4[2 * (DQK_ / 4) + d4];
        float4 r3v = in4[3 * (DQK_ / 4) + d4];
#pragma unroll
        for (int e = 0; e < 4; ++e) {
            float w = W[(size_t)(4 * d4 + e) * H_ + t];   // coalesced
            acc0 = fmaf(reinterpret_cast<const float*>(&r0v)[e], w, acc0);
            acc1 = fmaf(reinterpret_cast<const float*>(&r1v)[e], w, acc1);
            acc2 = fmaf(reinterpret_cast<const float*>(&r2v)[e], w, acc2);
            acc3 = fmaf(reinterpret_cast<const float*>(&r3v)[e], w, acc3);
        }
    }
    float e0 = __builtin_amdgcn_exp2f(acc0 * TANH_C);
    float e1 = __builtin_amdgcn_exp2f(acc1 * TANH_C);
    float e2 = __builtin_amdgcn_exp2f(acc2 * TANH_C);
    float e3 = __builtin_amdgcn_exp2f(acc3 * TANH_C);
    if (isq) {
        eq[(size_t)(r0 + 0) * H_ + t] = e0;
        eq[(size_t)(r0 + 1) * H_ + t] = e1;
        eq[(size_t)(r0 + 2) * H_ + t] = e2;
        eq[(size_t)(r0 + 3) * H_ + t] = e3;
    } else {
        const int b  = r0 >> 9;
        const int k0 = r0 & (LK_ - 1);
        float* o = ekT + ((size_t)(b * H_ + t)) * LK_ + k0;
        *reinterpret_cast<float4*>(o) = make_float4(e0, e1, e2, e3);
    }
}

// ---------------------------------------------------------------------------
// attn_kernel (R9 body + cold-miss stagger): one block per (b, q-tile of 4).
//   Phase B h-loop starts at offset (qt&15) within each 16-slice.
//   Phase D wave->k-slice map rotated by qt (bijective).
// ---------------------------------------------------------------------------
__global__ __launch_bounds__(1024) void attn_kernel(
    const float* __restrict__ eq,          // [B*LQ, H]
    const float* __restrict__ ekT,         // [B, H, LK]
    const float* __restrict__ wv,          // [H]
    const float* __restrict__ values,      // [B, LK, DV]
    const int*   __restrict__ valid_lens,  // [B]
    float* __restrict__ out) {             // [B*LQ, DV]
    __shared__ float eq_l[4][H_];          // 2 KB
    __shared__ float wm2[H_];              // 512 B
    __shared__ float sc[LK_][4];           // 8 KB (e-values, [k][row])
    __shared__ float scratch[8 * 128 * 20];// 80 KB: partB then partD
    __shared__ float red[16];
    __shared__ float inv_s[4];

    float (*partB)[128][20] = reinterpret_cast<float (*)[128][20]>(scratch);
    float (*partD)[4][DV_]  = reinterpret_cast<float (*)[4][DV_]>(scratch);

    const int blk = blockIdx.x;            // b*64 + qt
    const int b   = blk >> 6;
    const int qt  = blk & 63;
    const int t   = threadIdx.x;

    if (t < 512) {
        eq_l[t >> 7][t & 127] = eq[(size_t)(b * LQ_ + qt * 4 + (t >> 7)) * H_ + (t & 127)];
    } else if (t < 640) {
        wm2[t - 512] = -2.f * wv[t - 512];
    }
    __syncthreads();

    const int valid = valid_lens[b];

    // ---- Phase B: register-blocked partial scores (h start staggered) ----
    {
        const int quad = t & 127;          // k-quad: k = 4*quad + e
        const int hs   = t >> 7;           // h-slice: h = 16*hs + hh
        const int k0   = 4 * quad;
        const int rot  = qt & 15;          // per-block h rotation
        float acc[16];
#pragma unroll
        for (int i = 0; i < 16; ++i) acc[i] = 0.f;

        if (k0 < valid) {
            const float* ekb = ekT + (size_t)b * H_ * LK_ + k0;
#pragma unroll 2
            for (int hh = 0; hh < 16; ++hh) {
                const int h = 16 * hs + ((hh + rot) & 15);
                float4 ek = *reinterpret_cast<const float4*>(ekb + (size_t)h * LK_);
                float w = wm2[h];          // LDS broadcast
#pragma unroll
                for (int r = 0; r < 4; ++r) {
                    float qv = eq_l[r][h]; // LDS broadcast
                    acc[4 * r + 0] = fmaf(w, __builtin_amdgcn_rcpf(fmaf(qv, ek.x, 1.f)), acc[4 * r + 0]);
                    acc[4 * r + 1] = fmaf(w, __builtin_amdgcn_rcpf(fmaf(qv, ek.y, 1.f)), acc[4 * r + 1]);
                    acc[4 * r + 2] = fmaf(w, __builtin_amdgcn_rcpf(fmaf(qv, ek.z, 1.f)), acc[4 * r + 2]);
                    acc[4 * r + 3] = fmaf(w, __builtin_amdgcn_rcpf(fmaf(qv, ek.w, 1.f)), acc[4 * r + 3]);
                }
            }
        }
        float* pb = &partB[hs][quad][0];
#pragma unroll
        for (int i = 0; i < 4; ++i)
            *reinterpret_cast<float4*>(pb + 4 * i) = *reinterpret_cast<float4*>(&acc[4 * i]);
    }
    __syncthreads();

    // ---- Score stage: reduce 8 h-slices, exp2, mask -> sc[k][r] ----
#pragma unroll
    for (int j = 0; j < 2; ++j) {
        const int o    = t + 1024 * j;     // 0..2047
        const int quad = o >> 4;
        const int idx  = o & 15;           // r*4 + e
        const int k    = 4 * quad + (idx & 3);
        float s = 0.f;
#pragma unroll
        for (int hs = 0; hs < 8; ++hs) s += partB[hs][quad][idx];
        sc[k][idx >> 2] = (k < valid) ? __builtin_amdgcn_exp2f(s * L2E) : 0.f;
    }
    __syncthreads();

    // ---- Phase C: per-row sum only (wave w -> row qi = w>>2) ----
    const int qi = t >> 8;                 // 0..3 wave-uniform
    const int kl = t & 255;
    {
        float ss = sc[kl][qi] + sc[kl + 256][qi];
#pragma unroll
        for (int off = 32; off; off >>= 1) ss += __shfl_down(ss, off, 64);
        if ((t & 63) == 0) red[t >> 6] = ss;
    }
    __syncthreads();
    if (t < 4) {
        inv_s[t] = 1.f / (red[4 * t] + red[4 * t + 1] + red[4 * t + 2] + red[4 * t + 3]);
    }
    __syncthreads();                        // also fences partB before partD reuse

    // ---- Phase D: out = attn @ values (wave->k-slice rotated by qt) ----
    {
        const int w  = __builtin_amdgcn_readfirstlane((int)(((t >> 6) + qt) & 15)); // rotated wave slot
        const int v  = 4 * (t & 63);
        const int kstart = 32 * w;
        const int kend   = min(kstart + 32, valid);
        const int wslot  = t >> 6;          // physical wave for partD indexing
        const float* vb = values + (size_t)b * LK_ * DV_ + v;
        float4 a0 = make_float4(0.f, 0.f, 0.f, 0.f);
        float4 a1 = a0, a2 = a0, a3 = a0;
#pragma unroll 2
        for (int k = kstart; k < kend; ++k) {
            float4 sv = *reinterpret_cast<const float4*>(&sc[k][0]);     // broadcast
            float4 vv = *reinterpret_cast<const float4*>(vb + (size_t)k * DV_); // coalesced
            a0.x = fmaf(sv.x, vv.x, a0.x); a0.y = fmaf(sv.x, vv.y, a0.y);
            a0.z = fmaf(sv.x, vv.z, a0.z); a0.w = fmaf(sv.x, vv.w, a0.w);
            a1.x = fmaf(sv.y, vv.x, a1.x); a1.y = fmaf(sv.y, vv.y, a1.y);
            a1.z = fmaf(sv.y, vv.z, a1.z); a1.w = fmaf(sv.y, vv.w, a1.w);
            a2.x = fmaf(sv.z, vv.x, a2.x); a2.y = fmaf(sv.z, vv.y, a2.y);
            a2.z = fmaf(sv.z, vv.z, a2.z); a2.w = fmaf(sv.z, vv.w, a2.w);
            a3.x = fmaf(sv.w, vv.x, a3.x); a3.y = fmaf(sv.w, vv.y, a3.y);
            a3.z = fmaf(sv.w, vv.z, a3.z); a3.w = fmaf(sv.w, vv.w, a3.w);
        }
        *reinterpret_cast<float4*>(&partD[wslot][0][v]) = a0;
        *reinterpret_cast<float4*>(&partD[wslot][1][v]) = a1;
        *reinterpret_cast<float4*>(&partD[wslot][2][v]) = a2;
        *reinterpret_cast<float4*>(&partD[wslot][3][v]) = a3;
    }
    __syncthreads();
    {
        const int r = t >> 8;
        const int v = t & 255;
        float s = 0.f;
#pragma unroll
        for (int w = 0; w < 16; ++w) s += partD[w][r][v];
        out[(size_t)(b * LQ_ + qt * 4 + r) * DV_ + v] = s * inv_s[r];
    }
}

extern "C" void kernel_launch(void* const* d_in, const int* in_sizes, int n_in,
                              void* d_out, int out_size, void* d_ws, size_t ws_size,
                              hipStream_t stream) {
    const float* queries    = (const float*)d_in[0];  // [B, LQ, DQ]
    const float* keys       = (const float*)d_in[1];  // [B, LK, DK]
    const float* values     = (const float*)d_in[2];  // [B, LK, DV]
    const float* Wq         = (const float*)d_in[3];  // [DQ, H]
    const float* Wk         = (const float*)d_in[4];  // [DK, H]
    const float* wv         = (const float*)d_in[5];  // [H]
    const int*   valid_lens = (const int*)d_in[6];    // [B]
    float* out = (float*)d_out;

    float* eq    = (float*)d_ws;                   // [B*LQ, H]   512 KB
    float* ekT   = eq + (size_t)B_ * LQ_ * H_;     // [B, H, LK]  1 MB
    float* dummy = ekT + (size_t)B_ * H_ * LK_;    // [64] dead scratch

    proj_kernel<<<NQBLK + NKBLK + NPREF, 128, 0, stream>>>(queries, keys, Wq, Wk,
                                                           values, eq, ekT, dummy);
    attn_kernel<<<B_ * LQ_ / 4, 1024, 0, stream>>>(eq, ekT, wv, values, valid_lens, out);
}